// Round 14
// baseline (71.567 us; speedup 1.0000x reference)
//
#include <hip/hip_runtime.h>

// RNN-T (transducer) loss, B=8 T=256 U=96 H=512, f32.
// Linear-domain wavefront DP: A[t,u] = A[t-1,u]*Wb[t-1,u] + A[t,u-1]*We[t,u-1]
// Wb=exp(blank_lp), We=exp(emit_lp) precomputed by k_lse into diagonal layout:
// Wb(t,u) -> row t+u, col u, slot0;  We(t,u) -> row t+u, col u+1, slot1.
// k_init zeroes the ENTIRE D buffer first (guaranteed coverage; zero weight
// self-masks every dead/unwritten cell) -> k_lse writes only live slots.
constexpr int B = 8, T = 256, U = 96, H = 512;
constexpr int RW = 96, ROWS = 368;   // float2 {wb,we} per cell
constexpr int CH = 12;               // rows per k_lse chunk (straggler bound)

typedef float vf4 __attribute__((ext_vector_type(4)));

__device__ __forceinline__ float exp2i(int e) {      // e in [-126,127]
    return __uint_as_float((unsigned)(127 + e) << 23);
}

// Zero-fill the whole weight buffer (exp(-inf)=0 for never-written cells).
__global__ __launch_bounds__(256) void k_init(float* __restrict__ D) {
    vf4 z = {0.f, 0.f, 0.f, 0.f};
    ((vf4*)D)[blockIdx.x * 256 + threadIdx.x] = z;
}

// Fetch row element i (uniform per half) from a 32-lane half's registers.
__device__ __forceinline__ float half_get(vf4 a, vf4 b, vf4 c, vf4 d,
                                          int i, int h) {
    vf4 p = (i & 128) ? ((i & 256) ? d : b) : ((i & 256) ? c : a);
    int m = i & 3;
    float e = (m == 0) ? p.x : (m == 1) ? p.y : (m == 2) ? p.z : p.w;
    return __shfl(e, (h << 5) | ((i >> 2) & 31));
}

// Kernel 1: one wave per 12-row chunk (chunk fits one (b,t)), 2 rows at a
// time via 32-lane halves (5-level reduce). Dead chunks exit immediately;
// no zeroing needed (k_init covered everything).
__global__ __launch_bounds__(256, 8) void k_lse(
    const float* __restrict__ x, const int* __restrict__ label,
    const int* __restrict__ f_len, const int* __restrict__ y_len,
    const int* __restrict__ blank_p, const float* __restrict__ lam_p,
    float* __restrict__ D)
{
    const int tid  = threadIdx.x;
    const int lane = tid & 63;
    const int l32  = lane & 31;
    const int h    = lane >> 5;
    const int chunk = (blockIdx.x << 2) | (tid >> 6);   // 0..16383
    const int b  = chunk & 7;                 // b fastest: balanced dead work
    const int t  = (chunk >> 3) & 255;
    const int u0 = (chunk >> 11) * CH;        // 0,12,...,84

    const int fb = f_len[b], yb = y_len[b];
    if (t >= fb || u0 > yb) return;                    // dead chunk
    const int nbl = min(CH, yb + 1 - u0);              // rows with Wb write
    const int nem = min(CH, yb - u0);                  // rows with We write

    const int ib   = blank_p[0];
    const float lam = lam_p[0];
    const float pen = lam * ((fb - 1.0f) * 0.5f) - lam * (float)t;

    int lbl_l = 0;                                     // labels u0..u0+11
    if (lane < CH && (u0 + lane) < U - 1)
        lbl_l = label[b * (U - 1) + u0 + lane];

    const float* xrow = x + ((size_t)(b * T + t) * U + u0) * H;
    size_t cc0 = ((size_t)b * ROWS + (t + u0)) * RW + u0;

    for (int i = 0; i < nbl; i += 2) {
        int row = i + h;                   // half h handles row i+h
        bool rv = row < nbl;
        const float* xr = xrow + (size_t)row * H;
        vf4 v0 = {0,0,0,0}, v1 = v0, v2 = v0, v3 = v0;
        if (rv) {
            v0 = __builtin_nontemporal_load((const vf4*)xr + l32);
            v1 = __builtin_nontemporal_load((const vf4*)xr + l32 + 32);
            v2 = __builtin_nontemporal_load((const vf4*)xr + l32 + 64);
            v3 = __builtin_nontemporal_load((const vf4*)xr + l32 + 96);
        }
        float s = __expf(v0.x) + __expf(v0.y) + __expf(v0.z) + __expf(v0.w)
                + __expf(v1.x) + __expf(v1.y) + __expf(v1.z) + __expf(v1.w)
                + __expf(v2.x) + __expf(v2.y) + __expf(v2.z) + __expf(v2.w)
                + __expf(v3.x) + __expf(v3.y) + __expf(v3.z) + __expf(v3.w);
        #pragma unroll
        for (int d = 1; d < 32; d <<= 1) s += __shfl_xor(s, d);
        float rcp = __builtin_amdgcn_rcpf(s);          // W = exp(x)/s

        float xb = half_get(v0, v1, v2, v3, ib, h);
        int  lbl = __shfl(lbl_l, min(row, CH - 1));
        float xl = half_get(v0, v1, v2, v3, lbl, h);

        size_t cc = cc0 + (size_t)row * (RW + 1);
        if (rv && l32 == 0) D[cc * 2] = __expf(xb) * rcp;
        if (rv && row < nem && l32 == 1)
            D[(cc + 1) * 2 + 1] = __expf(xl + pen) * rcp;
    }
}

// Kernel 2: wavefront DP. One wave per batch. Lane l (0..11) owns the u-strip
// [8l, 8l+7]. Cross-lane shuffle is software-pipelined: n7 computed first,
// its shfl issues immediately, consumed by the NEXT step's n0.
// Stale-by-one-group power-of-2 rescale, bias 2^100 (a7s rescaled too).
__global__ __launch_bounds__(64) void k_alpha(
    const float* __restrict__ D_all,
    const int* __restrict__ f_len, const int* __restrict__ y_len,
    float* __restrict__ out)
{
    const int b = blockIdx.x;
    const int l = threadIdx.x;
    const float* D = D_all + (size_t)b * ROWS * RW * 2;
    const vf4* Dv = (const vf4*)D;                    // 48 vf4 per diag row
    const int lc = (l < 12) ? l : 11;
    const int fcap = f_len[b] - 1;
    const int ycap = y_len[b];
    const int kstar = fcap + ycap;                    // in [135, 350]
    const int gstar = (kstar - 1) >> 3;               // group holding kstar

    float A[8];
    #pragma unroll
    for (int c = 0; c < 8; ++c) A[c] = 0.f;
    if (l == 0) A[0] = 1.f;                           // alpha[0,0] = 1
    float a7s = __shfl_up(A[7], 1);                   // left col 8l-1 value (0)
    int ls_e = 0, E_prev = 0, fls = 0;
    float fin = 0.f;

    vf4 Wa[8][4], Wb[8][4];
    #pragma unroll
    for (int r = 0; r < 8; ++r)
        #pragma unroll
        for (int q = 0; q < 4; ++q)
            Wa[r][q] = Dv[(size_t)r * (RW / 2) + lc * 4 + q];   // rows 0..7

    #define STEP(WROW)                                                    \
    {                                                                     \
        float n7 = fmaf(A[6], (WROW)[3].w, A[7] * (WROW)[3].z);           \
        float n0 = fmaf(a7s,  (WROW)[0].y, A[0] * (WROW)[0].x);           \
        float n1 = fmaf(A[0], (WROW)[0].w, A[1] * (WROW)[0].z);           \
        float n2 = fmaf(A[1], (WROW)[1].y, A[2] * (WROW)[1].x);           \
        float n3 = fmaf(A[2], (WROW)[1].w, A[3] * (WROW)[1].z);           \
        float n4 = fmaf(A[3], (WROW)[2].y, A[4] * (WROW)[2].x);           \
        float n5 = fmaf(A[4], (WROW)[2].w, A[5] * (WROW)[2].z);           \
        float n6 = fmaf(A[5], (WROW)[3].y, A[6] * (WROW)[3].x);           \
        a7s = __shfl_up(n7, 1);                                           \
        A[0]=n0; A[1]=n1; A[2]=n2; A[3]=n3;                               \
        A[4]=n4; A[5]=n5; A[6]=n6; A[7]=n7;                               \
    }

    #define LEAN(CUR, NXT, gg)                                            \
    {                                                                     \
        _Pragma("unroll") for (int r = 0; r < 8; ++r)                     \
            _Pragma("unroll") for (int q = 0; q < 4; ++q)                 \
                NXT[r][q] = Dv[((size_t)((gg)+1)*8 + r)*(RW/2) + lc*4 + q]; \
        _Pragma("unroll") for (int r = 0; r < 8; ++r) STEP(CUR[r]);       \
        int sh = 100 - E_prev;                                            \
        float r1 = exp2i(sh >> 1), r2 = exp2i(sh - (sh >> 1));            \
        _Pragma("unroll") for (int c = 0; c < 8; ++c) A[c] = A[c]*r1*r2;  \
        a7s = a7s * r1 * r2;                                              \
        ls_e += E_prev - 100;                                             \
        float m = fmaxf(fmaxf(fmaxf(A[0],A[1]), fmaxf(A[2],A[3])),        \
                        fmaxf(fmaxf(A[4],A[5]), fmaxf(A[6],A[7])));       \
        m = (l < 12) ? m : 0.f;                                           \
        m = fmaxf(m, __shfl_xor(m, 1));                                   \
        m = fmaxf(m, __shfl_xor(m, 2));                                   \
        m = fmaxf(m, __shfl_xor(m, 4));                                   \
        m = fmaxf(m, __shfl_xor(m, 8));                                   \
        E_prev = (int)((__float_as_uint(m) >> 23) & 0xff) - 127;          \
    }

    #define CAPTURE(CUR, gg)                                              \
    {                                                                     \
        _Pragma("unroll") for (int r = 0; r < 8; ++r) {                   \
            STEP(CUR[r]);                                                 \
            int k = (gg) * 8 + r + 1;                                     \
            if (k == kstar) {                                             \
                int yc = ycap & 7;                                        \
                float f = (yc==0)?A[0]:(yc==1)?A[1]:(yc==2)?A[2]:         \
                          (yc==3)?A[3]:(yc==4)?A[4]:(yc==5)?A[5]:         \
                          (yc==6)?A[6]:A[7];                              \
                fin = (l == (ycap >> 3)) ? f : 0.f;                       \
                fls = ls_e;                                               \
            }                                                             \
        }                                                                 \
    }

    int gg = 0;
    while (true) {
        if (gg == gstar) { CAPTURE(Wa, gg); break; }
        LEAN(Wa, Wb, gg); gg++;
        if (gg == gstar) { CAPTURE(Wb, gg); break; }
        LEAN(Wb, Wa, gg); gg++;
    }
    #undef STEP
    #undef LEAN
    #undef CAPTURE

    float fv = __shfl(fin, ycap >> 3);
    int   fe = __shfl(fls, ycap >> 3);
    if (l == 0) {
        float wbf = D[((size_t)kstar * RW + ycap) * 2];   // e^{blank[fcap,ycap]}
        out[b] = -(__logf(fv) + (float)fe * 0.69314718056f + __logf(wbf));
    }
}

extern "C" void kernel_launch(void* const* d_in, const int* in_sizes, int n_in,
                              void* d_out, int out_size, void* d_ws, size_t ws_size,
                              hipStream_t stream) {
    const float* x      = (const float*)d_in[0];
    const int*   label  = (const int*)d_in[1];
    const int*   f_len  = (const int*)d_in[2];
    const int*   y_len  = (const int*)d_in[3];
    const int*   blankp = (const int*)d_in[4];
    const float* lamp   = (const float*)d_in[5];
    float* out = (float*)d_out;

    float* D = (float*)d_ws;                          // B*ROWS*RW*2 floats

    const int dfloats = B * ROWS * RW * 2;            // 565248
    k_init<<<dfloats / 4 / 256, 256, 0, stream>>>(D); // 552 blocks
    k_lse<<<4096, 256, 0, stream>>>(x, label, f_len, y_len, blankp, lamp, D);
    k_alpha<<<B, 64, 0, stream>>>(D, f_len, y_len, out);
}

// Round 15
// 71.241 us; speedup vs baseline: 1.0046x; 1.0046x over previous
//
#include <hip/hip_runtime.h>

// RNN-T (transducer) loss, B=8 T=256 U=96 H=512, f32.
// Linear-domain wavefront DP: A[t,u] = A[t-1,u]*Wb[t-1,u] + A[t,u-1]*We[t,u-1]
// Wb=exp(blank_lp), We=exp(emit_lp) precomputed by k_lse into diagonal layout:
// Wb(t,u) -> row t+u, col u, slot0;  We(t,u) -> row t+u, col u+1, slot1.
// hipMemsetAsync zeroes the ENTIRE D buffer first (guaranteed coverage; zero
// weight self-masks every dead/unwritten cell) -> k_lse writes only live slots.
constexpr int B = 8, T = 256, U = 96, H = 512;
constexpr int RW = 96, ROWS = 368;   // float2 {wb,we} per cell
constexpr int CH = 12;               // rows per k_lse chunk (straggler bound)

typedef float vf4 __attribute__((ext_vector_type(4)));

__device__ __forceinline__ float exp2i(int e) {      // e in [-126,127]
    return __uint_as_float((unsigned)(127 + e) << 23);
}

// Kernel 1: one wave per 12-row chunk (chunk fits one (b,t)); 4 rows per
// iteration via 16-lane quarters (4-level reduce). Interleaved vf4 mapping:
// lane l16 holds vf4 indices l16+16j -> coalesced 256B segments per quarter.
// Blank/label scalars are re-loaded directly by the storing lane (no
// cross-lane extraction); that load's latency hides under the exp+reduce.
__global__ __launch_bounds__(256) void k_lse(
    const float* __restrict__ x, const int* __restrict__ label,
    const int* __restrict__ f_len, const int* __restrict__ y_len,
    const int* __restrict__ blank_p, const float* __restrict__ lam_p,
    float* __restrict__ D)
{
    const int tid  = threadIdx.x;
    const int lane = tid & 63;
    const int l16  = lane & 15;
    const int q    = lane >> 4;               // quarter id = row offset
    const int chunk = (blockIdx.x << 2) | (tid >> 6);   // 0..16383
    const int b  = chunk & 7;                 // b fastest: balanced dead work
    const int t  = (chunk >> 3) & 255;
    const int u0 = (chunk >> 11) * CH;        // 0,12,...,84

    const int fb = f_len[b], yb = y_len[b];
    if (t >= fb || u0 > yb) return;                    // dead chunk
    const int nbl = min(CH, yb + 1 - u0);              // rows with Wb write
    const int nem = min(CH, yb - u0);                  // rows with We write

    const int ib   = blank_p[0];
    const float lam = lam_p[0];
    const float pen = lam * ((fb - 1.0f) * 0.5f) - lam * (float)t;

    int lbl_l = 0;                                     // labels u0..u0+11
    if (lane < CH && (u0 + lane) < U - 1)
        lbl_l = label[b * (U - 1) + u0 + lane];

    const float* xrow = x + ((size_t)(b * T + t) * U + u0) * H;
    size_t cc0 = ((size_t)b * ROWS + (t + u0)) * RW + u0;

    for (int i = 0; i < nbl; i += 4) {
        const int row = i + q;                 // quarter q handles row i+q
        const bool rv = row < nbl;
        const float* xr = xrow + (size_t)row * H;

        // scalar pre-load for the two storer lanes (latency hidden below)
        int  lbl = __shfl(lbl_l, row & 15);
        int  idx = (l16 == 0) ? ib : lbl;
        float xs = 0.f;
        if (rv && l16 < 2) xs = xr[idx];

        vf4 v[8];
        #pragma unroll
        for (int j = 0; j < 8; ++j) {
            vf4 z = {0.f, 0.f, 0.f, 0.f};
            v[j] = rv ? __builtin_nontemporal_load((const vf4*)xr + l16 + 16 * j)
                      : z;
        }
        float s0 = 0.f, s1 = 0.f, s2 = 0.f, s3 = 0.f;
        #pragma unroll
        for (int j = 0; j < 8; ++j) {
            s0 += __expf(v[j].x); s1 += __expf(v[j].y);
            s2 += __expf(v[j].z); s3 += __expf(v[j].w);
        }
        float s = (s0 + s1) + (s2 + s3);
        #pragma unroll
        for (int d = 1; d < 16; d <<= 1) s += __shfl_xor(s, d);
        float rcp = __builtin_amdgcn_rcpf(s);          // W = exp(x)/s

        size_t cc = cc0 + (size_t)row * (RW + 1);
        if (rv && l16 == 0) D[cc * 2] = __expf(xs) * rcp;            // Wb
        if (rv && row < nem && l16 == 1)
            D[(cc + 1) * 2 + 1] = __expf(xs + pen) * rcp;            // We
    }
}

// Kernel 2: wavefront DP (R14-proven). One wave per batch. Lane l (0..11)
// owns the u-strip [8l, 8l+7]. Cross-lane shuffle software-pipelined: n7
// computed first, its shfl issues immediately, consumed by NEXT step's n0.
// Stale-by-one-group power-of-2 rescale, bias 2^100 (a7s rescaled too).
__global__ __launch_bounds__(64) void k_alpha(
    const float* __restrict__ D_all,
    const int* __restrict__ f_len, const int* __restrict__ y_len,
    float* __restrict__ out)
{
    const int b = blockIdx.x;
    const int l = threadIdx.x;
    const float* D = D_all + (size_t)b * ROWS * RW * 2;
    const vf4* Dv = (const vf4*)D;                    // 48 vf4 per diag row
    const int lc = (l < 12) ? l : 11;
    const int fcap = f_len[b] - 1;
    const int ycap = y_len[b];
    const int kstar = fcap + ycap;                    // in [135, 350]
    const int gstar = (kstar - 1) >> 3;               // group holding kstar

    float A[8];
    #pragma unroll
    for (int c = 0; c < 8; ++c) A[c] = 0.f;
    if (l == 0) A[0] = 1.f;                           // alpha[0,0] = 1
    float a7s = __shfl_up(A[7], 1);                   // left col 8l-1 value (0)
    int ls_e = 0, E_prev = 0, fls = 0;
    float fin = 0.f;

    vf4 Wa[8][4], Wb[8][4];
    #pragma unroll
    for (int r = 0; r < 8; ++r)
        #pragma unroll
        for (int qq = 0; qq < 4; ++qq)
            Wa[r][qq] = Dv[(size_t)r * (RW / 2) + lc * 4 + qq];   // rows 0..7

    #define STEP(WROW)                                                    \
    {                                                                     \
        float n7 = fmaf(A[6], (WROW)[3].w, A[7] * (WROW)[3].z);           \
        float n0 = fmaf(a7s,  (WROW)[0].y, A[0] * (WROW)[0].x);           \
        float n1 = fmaf(A[0], (WROW)[0].w, A[1] * (WROW)[0].z);           \
        float n2 = fmaf(A[1], (WROW)[1].y, A[2] * (WROW)[1].x);           \
        float n3 = fmaf(A[2], (WROW)[1].w, A[3] * (WROW)[1].z);           \
        float n4 = fmaf(A[3], (WROW)[2].y, A[4] * (WROW)[2].x);           \
        float n5 = fmaf(A[4], (WROW)[2].w, A[5] * (WROW)[2].z);           \
        float n6 = fmaf(A[5], (WROW)[3].y, A[6] * (WROW)[3].x);           \
        a7s = __shfl_up(n7, 1);                                           \
        A[0]=n0; A[1]=n1; A[2]=n2; A[3]=n3;                               \
        A[4]=n4; A[5]=n5; A[6]=n6; A[7]=n7;                               \
    }

    #define LEAN(CUR, NXT, gg)                                            \
    {                                                                     \
        _Pragma("unroll") for (int r = 0; r < 8; ++r)                     \
            _Pragma("unroll") for (int qq = 0; qq < 4; ++qq)              \
                NXT[r][qq] = Dv[((size_t)((gg)+1)*8 + r)*(RW/2) + lc*4 + qq]; \
        _Pragma("unroll") for (int r = 0; r < 8; ++r) STEP(CUR[r]);       \
        int sh = 100 - E_prev;                                            \
        float r1 = exp2i(sh >> 1), r2 = exp2i(sh - (sh >> 1));            \
        _Pragma("unroll") for (int c = 0; c < 8; ++c) A[c] = A[c]*r1*r2;  \
        a7s = a7s * r1 * r2;                                              \
        ls_e += E_prev - 100;                                             \
        float m = fmaxf(fmaxf(fmaxf(A[0],A[1]), fmaxf(A[2],A[3])),        \
                        fmaxf(fmaxf(A[4],A[5]), fmaxf(A[6],A[7])));       \
        m = (l < 12) ? m : 0.f;                                           \
        m = fmaxf(m, __shfl_xor(m, 1));                                   \
        m = fmaxf(m, __shfl_xor(m, 2));                                   \
        m = fmaxf(m, __shfl_xor(m, 4));                                   \
        m = fmaxf(m, __shfl_xor(m, 8));                                   \
        E_prev = (int)((__float_as_uint(m) >> 23) & 0xff) - 127;          \
    }

    #define CAPTURE(CUR, gg)                                              \
    {                                                                     \
        _Pragma("unroll") for (int r = 0; r < 8; ++r) {                   \
            STEP(CUR[r]);                                                 \
            int k = (gg) * 8 + r + 1;                                     \
            if (k == kstar) {                                             \
                int yc = ycap & 7;                                        \
                float f = (yc==0)?A[0]:(yc==1)?A[1]:(yc==2)?A[2]:         \
                          (yc==3)?A[3]:(yc==4)?A[4]:(yc==5)?A[5]:         \
                          (yc==6)?A[6]:A[7];                              \
                fin = (l == (ycap >> 3)) ? f : 0.f;                       \
                fls = ls_e;                                               \
            }                                                             \
        }                                                                 \
    }

    int gg = 0;
    while (true) {
        if (gg == gstar) { CAPTURE(Wa, gg); break; }
        LEAN(Wa, Wb, gg); gg++;
        if (gg == gstar) { CAPTURE(Wb, gg); break; }
        LEAN(Wb, Wa, gg); gg++;
    }
    #undef STEP
    #undef LEAN
    #undef CAPTURE

    float fv = __shfl(fin, ycap >> 3);
    int   fe = __shfl(fls, ycap >> 3);
    if (l == 0) {
        float wbf = D[((size_t)kstar * RW + ycap) * 2];   // e^{blank[fcap,ycap]}
        out[b] = -(__logf(fv) + (float)fe * 0.69314718056f + __logf(wbf));
    }
}

extern "C" void kernel_launch(void* const* d_in, const int* in_sizes, int n_in,
                              void* d_out, int out_size, void* d_ws, size_t ws_size,
                              hipStream_t stream) {
    const float* x      = (const float*)d_in[0];
    const int*   label  = (const int*)d_in[1];
    const int*   f_len  = (const int*)d_in[2];
    const int*   y_len  = (const int*)d_in[3];
    const int*   blankp = (const int*)d_in[4];
    const float* lamp   = (const float*)d_in[5];
    float* out = (float*)d_out;

    float* D = (float*)d_ws;                          // B*ROWS*RW*2 floats

    hipMemsetAsync(D, 0, (size_t)B * ROWS * RW * 2 * sizeof(float), stream);
    k_lse<<<4096, 256, 0, stream>>>(x, label, f_len, y_len, blankp, lamp, D);
    k_alpha<<<B, 64, 0, stream>>>(D, f_len, y_len, out);
}

// Round 17
// 66.160 us; speedup vs baseline: 1.0817x; 1.0768x over previous
//
#include <hip/hip_runtime.h>

// RNN-T (transducer) loss, B=8 T=256 U=96 H=512, f32.
// Linear-domain wavefront DP: A[t,u] = A[t-1,u]*Wb[t-1,u] + A[t,u-1]*We[t,u-1]
// Wb=exp(blank_lp), We=exp(emit_lp) precomputed by k_lse into diagonal layout:
// Wb(t,u) -> row t+u, col u, slot0;  We(t,u) -> row t+u, col u+1, slot1.
// hipMemsetAsync zeroes the ENTIRE D buffer first (guaranteed coverage; zero
// weight self-masks every dead/unwritten cell) -> k_lse writes only live slots.
// k_alpha's cross-lane traffic is DPP (VALU), not ds_bpermute.
constexpr int B = 8, T = 256, U = 96, H = 512;
constexpr int RW = 96, ROWS = 368;   // float2 {wb,we} per cell
constexpr int CH = 12;               // rows per k_lse chunk (straggler bound)

typedef float vf4 __attribute__((ext_vector_type(4)));

__device__ __forceinline__ float exp2i(int e) {      // e in [-126,127]
    return __uint_as_float((unsigned)(127 + e) << 23);
}

// lane l <- x[lane l-1]; lane 0 <- 0.  Pure-VALU shfl_up(x,1): DPP wave_shr:1.
__device__ __forceinline__ float dpp_up1(float x) {
    return __int_as_float(__builtin_amdgcn_update_dpp(
        0, __float_as_int(x), 0x138, 0xf, 0xf, true));
}
// fmax with row_shr:N shifted self (accumulates max toward higher lanes).
template <int CTRL>
__device__ __forceinline__ float dpp_maxshr(float x) {
    return fmaxf(x, __int_as_float(__builtin_amdgcn_update_dpp(
        0, __float_as_int(x), CTRL, 0xf, 0xf, true)));
}

// Kernel 1 (R15-proven): one wave per 12-row chunk; 4 rows per iteration via
// 16-lane quarters (4-level reduce). Interleaved vf4 mapping: lane l16 holds
// vf4 indices l16+16j -> coalesced 256B segments per quarter. Blank/label
// scalars re-loaded directly by the storing lane (latency hidden under exps).
__global__ __launch_bounds__(256) void k_lse(
    const float* __restrict__ x, const int* __restrict__ label,
    const int* __restrict__ f_len, const int* __restrict__ y_len,
    const int* __restrict__ blank_p, const float* __restrict__ lam_p,
    float* __restrict__ D)
{
    const int tid  = threadIdx.x;
    const int lane = tid & 63;
    const int l16  = lane & 15;
    const int q    = lane >> 4;               // quarter id = row offset
    const int chunk = (blockIdx.x << 2) | (tid >> 6);   // 0..16383
    const int b  = chunk & 7;                 // b fastest: balanced dead work
    const int t  = (chunk >> 3) & 255;
    const int u0 = (chunk >> 11) * CH;        // 0,12,...,84

    const int fb = f_len[b], yb = y_len[b];
    if (t >= fb || u0 > yb) return;                    // dead chunk
    const int nbl = min(CH, yb + 1 - u0);              // rows with Wb write
    const int nem = min(CH, yb - u0);                  // rows with We write

    const int ib   = blank_p[0];
    const float lam = lam_p[0];
    const float pen = lam * ((fb - 1.0f) * 0.5f) - lam * (float)t;

    int lbl_l = 0;                                     // labels u0..u0+11
    if (lane < CH && (u0 + lane) < U - 1)
        lbl_l = label[b * (U - 1) + u0 + lane];

    const float* xrow = x + ((size_t)(b * T + t) * U + u0) * H;
    size_t cc0 = ((size_t)b * ROWS + (t + u0)) * RW + u0;

    for (int i = 0; i < nbl; i += 4) {
        const int row = i + q;                 // quarter q handles row i+q
        const bool rv = row < nbl;
        const float* xr = xrow + (size_t)row * H;

        // scalar pre-load for the two storer lanes (latency hidden below)
        int  lbl = __shfl(lbl_l, row & 15);
        int  idx = (l16 == 0) ? ib : lbl;
        float xs = 0.f;
        if (rv && l16 < 2) xs = xr[idx];

        vf4 v[8];
        #pragma unroll
        for (int j = 0; j < 8; ++j) {
            vf4 z = {0.f, 0.f, 0.f, 0.f};
            v[j] = rv ? __builtin_nontemporal_load((const vf4*)xr + l16 + 16 * j)
                      : z;
        }
        float s0 = 0.f, s1 = 0.f, s2 = 0.f, s3 = 0.f;
        #pragma unroll
        for (int j = 0; j < 8; ++j) {
            s0 += __expf(v[j].x); s1 += __expf(v[j].y);
            s2 += __expf(v[j].z); s3 += __expf(v[j].w);
        }
        float s = (s0 + s1) + (s2 + s3);
        #pragma unroll
        for (int d = 1; d < 16; d <<= 1) s += __shfl_xor(s, d);
        float rcp = __builtin_amdgcn_rcpf(s);          // W = exp(x)/s

        size_t cc = cc0 + (size_t)row * (RW + 1);
        if (rv && l16 == 0) D[cc * 2] = __expf(xs) * rcp;            // Wb
        if (rv && row < nem && l16 == 1)
            D[(cc + 1) * 2 + 1] = __expf(xs + pen) * rcp;            // We
    }
}

// Kernel 2: wavefront DP. One wave per batch. Lane l (0..11) owns the u-strip
// [8l, 8l+7]. Per step: 16 FMA + ONE DPP wave_shr:1 (VALU, ~4cyc) -- no
// ds_bpermute anywhere in the loop. Group rescale uses DPP row_shr max tree +
// readlane(15). Stale-by-one-group power-of-2 rescale, bias 2^100.
__global__ __launch_bounds__(64) void k_alpha(
    const float* __restrict__ D_all,
    const int* __restrict__ f_len, const int* __restrict__ y_len,
    float* __restrict__ out)
{
    const int b = blockIdx.x;
    const int l = threadIdx.x;
    const float* D = D_all + (size_t)b * ROWS * RW * 2;
    const vf4* Dv = (const vf4*)D;                    // 48 vf4 per diag row
    const int lc = (l < 12) ? l : 11;
    const int fcap = f_len[b] - 1;
    const int ycap = y_len[b];
    const int kstar = fcap + ycap;                    // in [135, 350]
    const int gstar = (kstar - 1) >> 3;               // group holding kstar

    float A[8];
    #pragma unroll
    for (int c = 0; c < 8; ++c) A[c] = 0.f;
    if (l == 0) A[0] = 1.f;                           // alpha[0,0] = 1
    float a7s = 0.f;                                  // col 8l-1 prev-diag value
    int ls_e = 0, E_prev = 0, fls = 0;
    float fin = 0.f;

    vf4 Wa[8][4], Wb[8][4];
    #pragma unroll
    for (int r = 0; r < 8; ++r)
        #pragma unroll
        for (int qq = 0; qq < 4; ++qq)
            Wa[r][qq] = Dv[(size_t)r * (RW / 2) + lc * 4 + qq];   // rows 0..7

    #define STEP(WROW)                                                    \
    {                                                                     \
        float n7 = fmaf(A[6], (WROW)[3].w, A[7] * (WROW)[3].z);           \
        float n0 = fmaf(a7s,  (WROW)[0].y, A[0] * (WROW)[0].x);           \
        float n1 = fmaf(A[0], (WROW)[0].w, A[1] * (WROW)[0].z);           \
        float n2 = fmaf(A[1], (WROW)[1].y, A[2] * (WROW)[1].x);           \
        float n3 = fmaf(A[2], (WROW)[1].w, A[3] * (WROW)[1].z);           \
        float n4 = fmaf(A[3], (WROW)[2].y, A[4] * (WROW)[2].x);           \
        float n5 = fmaf(A[4], (WROW)[2].w, A[5] * (WROW)[2].z);           \
        float n6 = fmaf(A[5], (WROW)[3].y, A[6] * (WROW)[3].x);           \
        a7s = dpp_up1(n7);                                                \
        A[0]=n0; A[1]=n1; A[2]=n2; A[3]=n3;                               \
        A[4]=n4; A[5]=n5; A[6]=n6; A[7]=n7;                               \
    }

    #define LEAN(CUR, NXT, gg)                                            \
    {                                                                     \
        _Pragma("unroll") for (int r = 0; r < 8; ++r)                     \
            _Pragma("unroll") for (int qq = 0; qq < 4; ++qq)              \
                NXT[r][qq] = Dv[((size_t)((gg)+1)*8 + r)*(RW/2) + lc*4 + qq]; \
        _Pragma("unroll") for (int r = 0; r < 8; ++r) STEP(CUR[r]);       \
        int sh = 100 - E_prev;                                            \
        float r1 = exp2i(sh >> 1), r2 = exp2i(sh - (sh >> 1));            \
        _Pragma("unroll") for (int c = 0; c < 8; ++c) A[c] = A[c]*r1*r2;  \
        a7s = a7s * r1 * r2;                                              \
        ls_e += E_prev - 100;                                             \
        float m = fmaxf(fmaxf(fmaxf(A[0],A[1]), fmaxf(A[2],A[3])),        \
                        fmaxf(fmaxf(A[4],A[5]), fmaxf(A[6],A[7])));       \
        m = dpp_maxshr<0x111>(m);   /* row_shr:1 */                       \
        m = dpp_maxshr<0x112>(m);   /* row_shr:2 */                       \
        m = dpp_maxshr<0x114>(m);   /* row_shr:4 */                       \
        m = dpp_maxshr<0x118>(m);   /* row_shr:8 -> lane15 = max(l0..15) */ \
        int mi = __builtin_amdgcn_readlane(__float_as_int(m), 15);        \
        E_prev = ((mi >> 23) & 0xff) - 127;                               \
    }

    #define CAPTURE(CUR, gg)                                              \
    {                                                                     \
        _Pragma("unroll") for (int r = 0; r < 8; ++r) {                   \
            STEP(CUR[r]);                                                 \
            int k = (gg) * 8 + r + 1;                                     \
            if (k == kstar) {                                             \
                int yc = ycap & 7;                                        \
                float f = (yc==0)?A[0]:(yc==1)?A[1]:(yc==2)?A[2]:         \
                          (yc==3)?A[3]:(yc==4)?A[4]:(yc==5)?A[5]:         \
                          (yc==6)?A[6]:A[7];                              \
                fin = (l == (ycap >> 3)) ? f : 0.f;                       \
                fls = ls_e;                                               \
            }                                                             \
        }                                                                 \
    }

    int gg = 0;
    while (true) {
        if (gg == gstar) { CAPTURE(Wa, gg); break; }
        LEAN(Wa, Wb, gg); gg++;
        if (gg == gstar) { CAPTURE(Wb, gg); break; }
        LEAN(Wb, Wa, gg); gg++;
    }
    #undef STEP
    #undef LEAN
    #undef CAPTURE

    float fv = __shfl(fin, ycap >> 3);
    int   fe = __shfl(fls, ycap >> 3);
    if (l == 0) {
        float wbf = D[((size_t)kstar * RW + ycap) * 2];   // e^{blank[fcap,ycap]}
        out[b] = -(__logf(fv) + (float)fe * 0.69314718056f + __logf(wbf));
    }
}

extern "C" void kernel_launch(void* const* d_in, const int* in_sizes, int n_in,
                              void* d_out, int out_size, void* d_ws, size_t ws_size,
                              hipStream_t stream) {
    const float* x      = (const float*)d_in[0];
    const int*   label  = (const int*)d_in[1];
    const int*   f_len  = (const int*)d_in[2];
    const int*   y_len  = (const int*)d_in[3];
    const int*   blankp = (const int*)d_in[4];
    const float* lamp   = (const float*)d_in[5];
    float* out = (float*)d_out;

    float* D = (float*)d_ws;                          // B*ROWS*RW*2 floats

    (void)hipMemsetAsync(D, 0, (size_t)B * ROWS * RW * 2 * sizeof(float), stream);
    k_lse<<<4096, 256, 0, stream>>>(x, label, f_len, y_len, blankp, lamp, D);
    k_alpha<<<B, 64, 0, stream>>>(D, f_len, y_len, out);
}

// Round 18
// 65.067 us; speedup vs baseline: 1.0999x; 1.0168x over previous
//
#include <hip/hip_runtime.h>

// RNN-T (transducer) loss, B=8 T=256 U=96 H=512, f32.
// Linear-domain wavefront DP: A[t,u] = A[t-1,u]*Wb[t-1,u] + A[t,u-1]*We[t,u-1]
// Wb=exp(blank_lp), We=exp(emit_lp) precomputed by k_lse into diagonal layout:
// Wb(t,u) -> row t+u, col u, slot0;  We(t,u) -> row t+u, col u+1, slot1.
// hipMemsetAsync zeroes the ENTIRE D buffer first (guaranteed coverage; zero
// weight self-masks every dead/unwritten cell) -> k_lse writes only live slots.
// k_alpha: DPP cross-lane + TRIPLE-buffered group prefetch (2 groups ahead).
constexpr int B = 8, T = 256, U = 96, H = 512;
constexpr int RW = 96, ROWS = 368;   // float2 {wb,we} per cell
constexpr int CH = 12;               // rows per k_lse chunk (straggler bound)

typedef float vf4 __attribute__((ext_vector_type(4)));

__device__ __forceinline__ float exp2i(int e) {      // e in [-126,127]
    return __uint_as_float((unsigned)(127 + e) << 23);
}

// lane l <- x[lane l-1]; lane 0 <- 0.  Pure-VALU shfl_up(x,1): DPP wave_shr:1.
__device__ __forceinline__ float dpp_up1(float x) {
    return __int_as_float(__builtin_amdgcn_update_dpp(
        0, __float_as_int(x), 0x138, 0xf, 0xf, true));
}
// fmax with row_shr:N shifted self (accumulates max toward higher lanes).
template <int CTRL>
__device__ __forceinline__ float dpp_maxshr(float x) {
    return fmaxf(x, __int_as_float(__builtin_amdgcn_update_dpp(
        0, __float_as_int(x), CTRL, 0xf, 0xf, true)));
}

// Kernel 1 (R15-proven): one wave per 12-row chunk; 4 rows per iteration via
// 16-lane quarters (4-level reduce). Interleaved vf4 mapping: lane l16 holds
// vf4 indices l16+16j -> coalesced 256B segments per quarter. Blank/label
// scalars re-loaded directly by the storing lane (latency hidden under exps).
__global__ __launch_bounds__(256) void k_lse(
    const float* __restrict__ x, const int* __restrict__ label,
    const int* __restrict__ f_len, const int* __restrict__ y_len,
    const int* __restrict__ blank_p, const float* __restrict__ lam_p,
    float* __restrict__ D)
{
    const int tid  = threadIdx.x;
    const int lane = tid & 63;
    const int l16  = lane & 15;
    const int q    = lane >> 4;               // quarter id = row offset
    const int chunk = (blockIdx.x << 2) | (tid >> 6);   // 0..16383
    const int b  = chunk & 7;                 // b fastest: balanced dead work
    const int t  = (chunk >> 3) & 255;
    const int u0 = (chunk >> 11) * CH;        // 0,12,...,84

    const int fb = f_len[b], yb = y_len[b];
    if (t >= fb || u0 > yb) return;                    // dead chunk
    const int nbl = min(CH, yb + 1 - u0);              // rows with Wb write
    const int nem = min(CH, yb - u0);                  // rows with We write

    const int ib   = blank_p[0];
    const float lam = lam_p[0];
    const float pen = lam * ((fb - 1.0f) * 0.5f) - lam * (float)t;

    int lbl_l = 0;                                     // labels u0..u0+11
    if (lane < CH && (u0 + lane) < U - 1)
        lbl_l = label[b * (U - 1) + u0 + lane];

    const float* xrow = x + ((size_t)(b * T + t) * U + u0) * H;
    size_t cc0 = ((size_t)b * ROWS + (t + u0)) * RW + u0;

    for (int i = 0; i < nbl; i += 4) {
        const int row = i + q;                 // quarter q handles row i+q
        const bool rv = row < nbl;
        const float* xr = xrow + (size_t)row * H;

        // scalar pre-load for the two storer lanes (latency hidden below)
        int  lbl = __shfl(lbl_l, row & 15);
        int  idx = (l16 == 0) ? ib : lbl;
        float xs = 0.f;
        if (rv && l16 < 2) xs = xr[idx];

        vf4 v[8];
        #pragma unroll
        for (int j = 0; j < 8; ++j) {
            vf4 z = {0.f, 0.f, 0.f, 0.f};
            v[j] = rv ? __builtin_nontemporal_load((const vf4*)xr + l16 + 16 * j)
                      : z;
        }
        float s0 = 0.f, s1 = 0.f, s2 = 0.f, s3 = 0.f;
        #pragma unroll
        for (int j = 0; j < 8; ++j) {
            s0 += __expf(v[j].x); s1 += __expf(v[j].y);
            s2 += __expf(v[j].z); s3 += __expf(v[j].w);
        }
        float s = (s0 + s1) + (s2 + s3);
        #pragma unroll
        for (int d = 1; d < 16; d <<= 1) s += __shfl_xor(s, d);
        float rcp = __builtin_amdgcn_rcpf(s);          // W = exp(x)/s

        size_t cc = cc0 + (size_t)row * (RW + 1);
        if (rv && l16 == 0) D[cc * 2] = __expf(xs) * rcp;            // Wb
        if (rv && row < nem && l16 == 1)
            D[(cc + 1) * 2 + 1] = __expf(xs + pen) * rcp;            // We
    }
}

// Kernel 2: wavefront DP. One wave per batch. Lane l (0..11) owns the u-strip
// [8l, 8l+7]. Per step: 16 FMA + ONE DPP wave_shr:1. Group prefetch is
// TRIPLE-buffered (issue loads for group g+2 before stepping group g) so the
// ~600cyc L3/HBM latency hides under ~540cyc of two groups' FMA work.
// Stale-by-one-group power-of-2 rescale, bias 2^100.
__global__ __launch_bounds__(64) void k_alpha(
    const float* __restrict__ D_all,
    const int* __restrict__ f_len, const int* __restrict__ y_len,
    float* __restrict__ out)
{
    const int b = blockIdx.x;
    const int l = threadIdx.x;
    const float* D = D_all + (size_t)b * ROWS * RW * 2;
    const vf4* Dv = (const vf4*)D;                    // 48 vf4 per diag row
    const int lc = (l < 12) ? l : 11;
    const int fcap = f_len[b] - 1;
    const int ycap = y_len[b];
    const int kstar = fcap + ycap;                    // in [135, 350]
    const int gstar = (kstar - 1) >> 3;               // group holding kstar (>=16)

    float A[8];
    #pragma unroll
    for (int c = 0; c < 8; ++c) A[c] = 0.f;
    if (l == 0) A[0] = 1.f;                           // alpha[0,0] = 1
    float a7s = 0.f;                                  // col 8l-1 prev-diag value
    int ls_e = 0, E_prev = 0, fls = 0;
    float fin = 0.f;

    vf4 W0[8][4], W1[8][4], W2[8][4];
    #pragma unroll
    for (int r = 0; r < 8; ++r)
        #pragma unroll
        for (int qq = 0; qq < 4; ++qq) {
            W0[r][qq] = Dv[(size_t)r * (RW / 2) + lc * 4 + qq];        // grp 0
            W1[r][qq] = Dv[(size_t)(8 + r) * (RW / 2) + lc * 4 + qq];  // grp 1
        }

    #define STEP(WROW)                                                    \
    {                                                                     \
        float n7 = fmaf(A[6], (WROW)[3].w, A[7] * (WROW)[3].z);           \
        float n0 = fmaf(a7s,  (WROW)[0].y, A[0] * (WROW)[0].x);           \
        float n1 = fmaf(A[0], (WROW)[0].w, A[1] * (WROW)[0].z);           \
        float n2 = fmaf(A[1], (WROW)[1].y, A[2] * (WROW)[1].x);           \
        float n3 = fmaf(A[2], (WROW)[1].w, A[3] * (WROW)[1].z);           \
        float n4 = fmaf(A[3], (WROW)[2].y, A[4] * (WROW)[2].x);           \
        float n5 = fmaf(A[4], (WROW)[2].w, A[5] * (WROW)[2].z);           \
        float n6 = fmaf(A[5], (WROW)[3].y, A[6] * (WROW)[3].x);           \
        a7s = dpp_up1(n7);                                                \
        A[0]=n0; A[1]=n1; A[2]=n2; A[3]=n3;                               \
        A[4]=n4; A[5]=n5; A[6]=n6; A[7]=n7;                               \
    }

    // Step group gg from CUR; load group gg+2 into NXT; stale rescale.
    #define LEAN(CUR, NXT, gg)                                            \
    {                                                                     \
        _Pragma("unroll") for (int r = 0; r < 8; ++r)                     \
            _Pragma("unroll") for (int qq = 0; qq < 4; ++qq)              \
                NXT[r][qq] = Dv[((size_t)((gg)+2)*8 + r)*(RW/2) + lc*4 + qq]; \
        _Pragma("unroll") for (int r = 0; r < 8; ++r) STEP(CUR[r]);       \
        int sh = 100 - E_prev;                                            \
        float r1 = exp2i(sh >> 1), r2 = exp2i(sh - (sh >> 1));            \
        _Pragma("unroll") for (int c = 0; c < 8; ++c) A[c] = A[c]*r1*r2;  \
        a7s = a7s * r1 * r2;                                              \
        ls_e += E_prev - 100;                                             \
        float m = fmaxf(fmaxf(fmaxf(A[0],A[1]), fmaxf(A[2],A[3])),        \
                        fmaxf(fmaxf(A[4],A[5]), fmaxf(A[6],A[7])));       \
        m = dpp_maxshr<0x111>(m);   /* row_shr:1 */                       \
        m = dpp_maxshr<0x112>(m);   /* row_shr:2 */                       \
        m = dpp_maxshr<0x114>(m);   /* row_shr:4 */                       \
        m = dpp_maxshr<0x118>(m);   /* row_shr:8 -> lane15 = max(l0..15) */ \
        int mi = __builtin_amdgcn_readlane(__float_as_int(m), 15);        \
        E_prev = ((mi >> 23) & 0xff) - 127;                               \
    }

    #define CAPTURE(CUR, gg)                                              \
    {                                                                     \
        _Pragma("unroll") for (int r = 0; r < 8; ++r) {                   \
            STEP(CUR[r]);                                                 \
            int k = (gg) * 8 + r + 1;                                     \
            if (k == kstar) {                                             \
                int yc = ycap & 7;                                        \
                float f = (yc==0)?A[0]:(yc==1)?A[1]:(yc==2)?A[2]:         \
                          (yc==3)?A[3]:(yc==4)?A[4]:(yc==5)?A[5]:         \
                          (yc==6)?A[6]:A[7];                              \
                fin = (l == (ycap >> 3)) ? f : 0.f;                       \
                fls = ls_e;                                               \
            }                                                             \
        }                                                                 \
    }

    int gg = 0;
    while (true) {
        if (gg == gstar) { CAPTURE(W0, gg); break; }
        LEAN(W0, W2, gg); gg++;                       // load grp gg+2
        if (gg == gstar) { CAPTURE(W1, gg); break; }
        LEAN(W1, W0, gg); gg++;
        if (gg == gstar) { CAPTURE(W2, gg); break; }
        LEAN(W2, W1, gg); gg++;
    }
    #undef STEP
    #undef LEAN
    #undef CAPTURE

    float fv = __shfl(fin, ycap >> 3);
    int   fe = __shfl(fls, ycap >> 3);
    if (l == 0) {
        float wbf = D[((size_t)kstar * RW + ycap) * 2];   // e^{blank[fcap,ycap]}
        out[b] = -(__logf(fv) + (float)fe * 0.69314718056f + __logf(wbf));
    }
}

extern "C" void kernel_launch(void* const* d_in, const int* in_sizes, int n_in,
                              void* d_out, int out_size, void* d_ws, size_t ws_size,
                              hipStream_t stream) {
    const float* x      = (const float*)d_in[0];
    const int*   label  = (const int*)d_in[1];
    const int*   f_len  = (const int*)d_in[2];
    const int*   y_len  = (const int*)d_in[3];
    const int*   blankp = (const int*)d_in[4];
    const float* lamp   = (const float*)d_in[5];
    float* out = (float*)d_out;

    float* D = (float*)d_ws;                          // B*ROWS*RW*2 floats

    (void)hipMemsetAsync(D, 0, (size_t)B * ROWS * RW * 2 * sizeof(float), stream);
    k_lse<<<4096, 256, 0, stream>>>(x, label, f_len, y_len, blankp, lamp, D);
    k_alpha<<<B, 64, 0, stream>>>(D, f_len, y_len, out);
}